// Round 2
// baseline (373.512 us; speedup 1.0000x reference)
//
#include <hip/hip_runtime.h>
#include <hip/hip_bf16.h>
#include <stdint.h>

typedef __attribute__((ext_vector_type(8))) short short8;
typedef __attribute__((ext_vector_type(4))) float f32x4;

#define MFMA16(a, b, c) __builtin_amdgcn_mfma_f32_16x16x32_bf16(a, b, c, 0, 0, 0)

#define D_ 512
#define M_ 16384
#define SREF 2048
#define QT 32
#define KT 64

__device__ __forceinline__ ushort f2bf(float f) {
  union { float f; uint32_t u; } v; v.f = f;
  uint32_t r = v.u + 0x7fffu + ((v.u >> 16) & 1u);
  return (ushort)(r >> 16);
}

__device__ __forceinline__ void gld16(const void* g, void* l) {
  __builtin_amdgcn_global_load_lds(
      (const __attribute__((address_space(1))) void*)g,
      (__attribute__((address_space(3))) void*)l, 16, 0, 0);
}

// ---------------- K0a: X fp32 -> bf16 ------------------------------------
__global__ __launch_bounds__(256) void conv_x_kernel(
    const float* __restrict__ X, ushort* __restrict__ Xb) {
  size_t i = ((size_t)blockIdx.x * 256 + threadIdx.x) * 8;
  float4 a = *(const float4*)(X + i);
  float4 c = *(const float4*)(X + i + 4);
  union { ushort u[8]; short8 v; } r;
  r.u[0] = f2bf(a.x); r.u[1] = f2bf(a.y); r.u[2] = f2bf(a.z); r.u[3] = f2bf(a.w);
  r.u[4] = f2bf(c.x); r.u[5] = f2bf(c.y); r.u[6] = f2bf(c.z); r.u[7] = f2bf(c.w);
  *(short8*)(Xb + i) = r.v;
}

// ---------------- K0b: W fp32 [k][n] -> bf16 W^T [z][n][k] ---------------
__global__ __launch_bounds__(256) void conv_wt_kernel(
    const float* __restrict__ Wq, const float* __restrict__ Wk,
    const float* __restrict__ Wv, ushort* __restrict__ Wt) {
  const int z = blockIdx.z;
  const float* W = (z == 0) ? Wq : ((z == 1) ? Wk : Wv);
  ushort* dst = Wt + (size_t)z * D_ * D_;
  const int k0 = blockIdx.x * 64, n0 = blockIdx.y * 64;
  __shared__ ushort T[64][72];
  const int r = threadIdx.x >> 3, c = (threadIdx.x & 7) * 8;
#pragma unroll
  for (int p = 0; p < 2; ++p) {
    int rr = p * 32 + r;  // k-local
    const float* src = W + (size_t)(k0 + rr) * D_ + n0 + c;
    float4 a = *(const float4*)src;
    float4 b = *(const float4*)(src + 4);
    T[c + 0][rr] = f2bf(a.x); T[c + 1][rr] = f2bf(a.y);
    T[c + 2][rr] = f2bf(a.z); T[c + 3][rr] = f2bf(a.w);
    T[c + 4][rr] = f2bf(b.x); T[c + 5][rr] = f2bf(b.y);
    T[c + 6][rr] = f2bf(b.z); T[c + 7][rr] = f2bf(b.w);
  }
  __syncthreads();
#pragma unroll
  for (int p = 0; p < 2; ++p) {
    int rr = p * 32 + r;  // n-local
    *(short8*)(dst + (size_t)(n0 + rr) * D_ + k0 + c) = *(const short8*)&T[rr][c];
  }
}

// ---------------- K1: fused QKV projection (3 GEMMs, one X pass) ---------
// z=0: Q -> ws[0]      [m][n] bf16
// z=1: K -> ws[M*D]    [m][n] bf16
// z=2: V -> ws[2*M*D]  TRANSPOSED [b][d][s] bf16 (coalesced via LDS bounce)
__global__ __launch_bounds__(256) void qkv_kernel(
    const ushort* __restrict__ Xb, const ushort* __restrict__ Wt,
    const float* __restrict__ bq, const float* __restrict__ bk,
    const float* __restrict__ bv, ushort* __restrict__ ws) {
  const int m0 = blockIdx.x * 64;
  const int n0 = blockIdx.y * 64;
  const int tid = threadIdx.x;
  const int lane = tid & 63;
  const int wid = tid >> 6;
  const int lr = lane & 15;
  const int lg = lane >> 4;
  const int m_base = (wid >> 1) * 32;
  const int n_base = (wid & 1) * 32;

  __shared__ union {
    struct { ushort At[64][32]; ushort Bt[3][64][32]; } s;
    ushort bounce[64][72];
  } u;

  f32x4 acc[3][2][2] = {};
  const int l4r = lane >> 2, l4c = (lane & 3) * 8;

  for (int ks = 0; ks < 16; ++ks) {
    const int k0 = ks * 32;
    gld16(Xb + (size_t)(m0 + wid * 16 + l4r) * D_ + k0 + l4c, &u.s.At[wid * 16][0]);
#pragma unroll
    for (int z = 0; z < 3; ++z)
      gld16(Wt + (size_t)z * D_ * D_ + (size_t)(n0 + wid * 16 + l4r) * D_ + k0 + l4c,
            &u.s.Bt[z][wid * 16][0]);
    __syncthreads();
    short8 a[2];
#pragma unroll
    for (int mf = 0; mf < 2; ++mf)
      a[mf] = *(const short8*)&u.s.At[m_base + mf * 16 + lr][lg * 8];
#pragma unroll
    for (int z = 0; z < 3; ++z) {
#pragma unroll
      for (int nf = 0; nf < 2; ++nf) {
        short8 b = *(const short8*)&u.s.Bt[z][n_base + nf * 16 + lr][lg * 8];
#pragma unroll
        for (int mf = 0; mf < 2; ++mf)
          acc[z][mf][nf] = MFMA16(a[mf], b, acc[z][mf][nf]);
      }
    }
    __syncthreads();
  }

  const int b_idx = m0 >> 11;
  const int s0 = m0 & 2047;
  // Q, K: direct row-major stores
#pragma unroll
  for (int z = 0; z < 2; ++z) {
    const float* bias = (z == 0) ? bq : bk;
    ushort* outp = ws + (size_t)z * M_ * D_;
#pragma unroll
    for (int mf = 0; mf < 2; ++mf) {
#pragma unroll
      for (int nf = 0; nf < 2; ++nf) {
        int n = n0 + n_base + nf * 16 + lr;
        float bvv = bias[n];
        int mrow = m_base + mf * 16 + lg * 4;
#pragma unroll
        for (int r = 0; r < 4; ++r)
          outp[(size_t)(m0 + mrow + r) * D_ + n] = f2bf(acc[z][mf][nf][r] + bvv);
      }
    }
  }
  // V: transpose via LDS bounce, coalesced store to [b][d][s]
#pragma unroll
  for (int mf = 0; mf < 2; ++mf) {
#pragma unroll
    for (int nf = 0; nf < 2; ++nf) {
      int nloc = n_base + nf * 16 + lr;
      float bvv = bv[n0 + nloc];
      int mrow = m_base + mf * 16 + lg * 4;
      ushort4 st;
      st.x = f2bf(acc[2][mf][nf][0] + bvv);
      st.y = f2bf(acc[2][mf][nf][1] + bvv);
      st.z = f2bf(acc[2][mf][nf][2] + bvv);
      st.w = f2bf(acc[2][mf][nf][3] + bvv);
      *(ushort4*)&u.bounce[nloc][mrow] = st;
    }
  }
  __syncthreads();
  ushort* vout = ws + 2 * (size_t)M_ * D_;
  const int rr = tid >> 3, cc = (tid & 7) * 8;
#pragma unroll
  for (int p = 0; p < 2; ++p) {
    int d = p * 32 + rr;
    *(short8*)(vout + ((size_t)b_idx * 512 + n0 + d) * 2048 + s0 + cc) =
        *(const short8*)&u.bounce[d][cc];
  }
}

// ---------------- K2: flash attention ------------------------------------
__global__ __launch_bounds__(512, 4) void attn_kernel(
    const ushort* __restrict__ Qg, const ushort* __restrict__ Kg,
    const ushort* __restrict__ Vtg, float* __restrict__ Out) {
  const int b = blockIdx.x & 7;                 // batch == XCD (round-robin)
  const int q0 = (blockIdx.x >> 3) * QT;
  const int tid = threadIdx.x;
  const int lane = tid & 63;
  const int wid = tid >> 6;
  const int lr = lane & 15;
  const int lg = lane >> 4;
  const int mfw = wid >> 2;  // 0..1  (S-tile m-frag of this wave)
  const int nfw = wid & 3;   // 0..3  (S-tile n-frag of this wave)

  // KV union: K view 64 rows x 1024B swizzled | Vt view 512 rows x 128B swizzled
  __shared__ __align__(16) ushort KVs[512 * 64];
  __shared__ __align__(16) float Ss[QT][68];
  __shared__ __align__(16) ushort Ps[QT][72];
  __shared__ float mstate[QT], lstate[QT], resc[QT];

  const ushort* Qrow = Qg + ((size_t)b * SREF + q0) * 512;
  const ushort* Krow = Kg + (size_t)b * SREF * 512;
  const ushort* Vrow = Vtg + (size_t)b * 512 * 2048;

  // Q A-fragments in registers (wave's 16 q-rows, full K=512): 64 VGPRs
  short8 qf[16];
  {
    const ushort* qp = Qrow + (size_t)(mfw * 16 + lr) * 512 + lg * 8;
#pragma unroll
    for (int ks = 0; ks < 16; ++ks) qf[ks] = *(const short8*)(qp + ks * 32);
  }
  if (tid < QT) { mstate[tid] = -1e30f; lstate[tid] = 0.0f; }

  f32x4 oacc[2][4] = {};
  __syncthreads();

  for (int kt = 0; kt < SREF / KT; ++kt) {
    const int kv0 = kt * KT;
    // phase A: stage K tile (64 rows x 1KB, pre-swizzled source)
    for (int ii = 0; ii < 8; ++ii) {
      int r = wid * 8 + ii;
      gld16(Krow + (size_t)(kv0 + r) * 512 + (size_t)((lane ^ (r & 7)) * 8), &KVs[r * 512]);
    }
    __syncthreads();

    // phase B: S = Q K^T (each wave one 16x16 frag of the 32x64 S-tile)
    {
      f32x4 sacc = {0.f, 0.f, 0.f, 0.f};
      const int krow = nfw * 16 + lr;
      const char* kbase = (const char*)KVs + krow * 1024;
      const int kx = (krow & 7) << 4;
#pragma unroll
      for (int ks = 0; ks < 16; ++ks) {
        short8 bb = *(const short8*)(kbase + (((ks * 64) + lg * 16) ^ kx));
        sacc = MFMA16(qf[ks], bb, sacc);
      }
#pragma unroll
      for (int r = 0; r < 4; ++r)
        Ss[mfw * 16 + lg * 4 + r][nfw * 16 + lr] = sacc[r];
    }
    __syncthreads();

    // phase C: async-stage V^T tile into KV union + cooperative online softmax
    {
      int rloc = lane >> 3;
      int csw = ((lane & 7) ^ rloc) * 8;
      for (int ii = 0; ii < 8; ++ii) {
        int i = wid * 8 + ii;
        gld16(Vrow + (size_t)(i * 8 + rloc) * 2048 + kv0 + csw, &KVs[i * 512]);
      }
    }
    {
      int row = tid >> 4, ic = tid & 15;
      float4 sv = *(const float4*)&Ss[row][ic * 4];
      const float scale = 0.04419417382415922f;  // 1/sqrt(512)
      float s0 = sv.x * scale, s1 = sv.y * scale, s2 = sv.z * scale, s3 = sv.w * scale;
      float mx = fmaxf(fmaxf(s0, s1), fmaxf(s2, s3));
#pragma unroll
      for (int off = 1; off < 16; off <<= 1) mx = fmaxf(mx, __shfl_xor(mx, off));
      float mold = mstate[row];
      float mnew = fmaxf(mold, mx);
      float p0 = __expf(s0 - mnew), p1 = __expf(s1 - mnew);
      float p2 = __expf(s2 - mnew), p3 = __expf(s3 - mnew);
      float psum = p0 + p1 + p2 + p3;
#pragma unroll
      for (int off = 1; off < 16; off <<= 1) psum += __shfl_xor(psum, off);
      ushort4 pb;
      pb.x = f2bf(p0); pb.y = f2bf(p1); pb.z = f2bf(p2); pb.w = f2bf(p3);
      *(ushort4*)&Ps[row][ic * 4] = pb;
      if (ic == 0) {
        float sc = __expf(mold - mnew);
        resc[row] = sc;
        mstate[row] = mnew;
        lstate[row] = lstate[row] * sc + psum;
      }
    }
    __syncthreads();

    // phase D: rescale O and accumulate P V   (wave owns d-chunk [wid*64, +64))
#pragma unroll
    for (int mf = 0; mf < 2; ++mf) {
      f32x4 rv;
#pragma unroll
      for (int r = 0; r < 4; ++r) rv[r] = resc[mf * 16 + lg * 4 + r];
#pragma unroll
      for (int nf = 0; nf < 4; ++nf) oacc[mf][nf] *= rv;
    }
#pragma unroll
    for (int kk = 0; kk < 2; ++kk) {
      short8 pA[2];
#pragma unroll
      for (int mf = 0; mf < 2; ++mf)
        pA[mf] = *(const short8*)&Ps[mf * 16 + lr][kk * 32 + lg * 8];
#pragma unroll
      for (int nf = 0; nf < 4; ++nf) {
        int vrow = wid * 64 + nf * 16 + lr;
        const char* vbase = (const char*)KVs + vrow * 128;
        short8 vB = *(const short8*)(vbase + (((kk * 64) + lg * 16) ^ ((vrow & 7) << 4)));
#pragma unroll
        for (int mf = 0; mf < 2; ++mf) oacc[mf][nf] = MFMA16(pA[mf], vB, oacc[mf][nf]);
      }
    }
    __syncthreads();
  }

  // epilogue: O / l
#pragma unroll
  for (int mf = 0; mf < 2; ++mf) {
#pragma unroll
    for (int r = 0; r < 4; ++r) {
      int row = mf * 16 + lg * 4 + r;
      float inv = 1.0f / lstate[row];
      float* op = Out + ((size_t)b * SREF + q0 + row) * 512 + wid * 64;
#pragma unroll
      for (int nf = 0; nf < 4; ++nf) op[nf * 16 + lr] = oacc[mf][nf][r] * inv;
    }
  }
}

extern "C" void kernel_launch(void* const* d_in, const int* in_sizes, int n_in,
                              void* d_out, int out_size, void* d_ws, size_t ws_size,
                              hipStream_t stream) {
  const float* X  = (const float*)d_in[0];
  const float* Wq = (const float*)d_in[1];
  const float* bq = (const float*)d_in[2];
  const float* Wk = (const float*)d_in[3];
  const float* bk = (const float*)d_in[4];
  const float* Wv = (const float*)d_in[5];
  const float* bv = (const float*)d_in[6];
  ushort* ws = (ushort*)d_ws;
  float* out = (float*)d_out;

  // d_out doubles as scratch for bf16 X and W^T until attn overwrites it.
  ushort* Xb = (ushort*)d_out;
  ushort* Wt = Xb + (size_t)M_ * D_;

  conv_x_kernel<<<dim3(M_ * D_ / (256 * 8)), dim3(256), 0, stream>>>(X, Xb);
  conv_wt_kernel<<<dim3(8, 8, 3), dim3(256), 0, stream>>>(Wq, Wk, Wv, Wt);

  dim3 g1(M_ / 64, D_ / 64), b1(256);
  qkv_kernel<<<g1, b1, 0, stream>>>(Xb, Wt, bq, bk, bv, ws);

  attn_kernel<<<dim3(512), dim3(512), 0, stream>>>(
      ws, ws + (size_t)M_ * D_, ws + 2 * (size_t)M_ * D_, out);
}

// Round 3
// 214.965 us; speedup vs baseline: 1.7375x; 1.7375x over previous
//
#include <hip/hip_runtime.h>
#include <hip/hip_bf16.h>
#include <stdint.h>

typedef __attribute__((ext_vector_type(8))) short short8;
typedef __attribute__((ext_vector_type(4))) float f32x4;

#define MFMA16(a, b, c) __builtin_amdgcn_mfma_f32_16x16x32_bf16(a, b, c, 0, 0, 0)

#define D_ 512
#define M_ 16384
#define SREF 2048
#define QT 64
#define KT 32
#define NT (SREF / KT)

#define VM12 asm volatile("s_waitcnt vmcnt(12)" ::: "memory")
#define VM8  asm volatile("s_waitcnt vmcnt(8)" ::: "memory")
#define VM4  asm volatile("s_waitcnt vmcnt(4)" ::: "memory")
#define VM0  asm volatile("s_waitcnt vmcnt(0)" ::: "memory")
#define BARRIER() do { asm volatile("s_waitcnt lgkmcnt(0)" ::: "memory"); \
                       __builtin_amdgcn_s_barrier(); \
                       asm volatile("" ::: "memory"); } while (0)

__device__ __forceinline__ ushort f2bf(float f) {
  union { float f; uint32_t u; } v; v.f = f;
  uint32_t r = v.u + 0x7fffu + ((v.u >> 16) & 1u);
  return (ushort)(r >> 16);
}

__device__ __forceinline__ void gld16(const void* g, void* l) {
  __builtin_amdgcn_global_load_lds(
      (const __attribute__((address_space(1))) void*)g,
      (__attribute__((address_space(3))) void*)l, 16, 0, 0);
}

// ---------------- K0a: X fp32 -> bf16 ------------------------------------
__global__ __launch_bounds__(256) void conv_x_kernel(
    const float* __restrict__ X, ushort* __restrict__ Xb) {
  size_t i = ((size_t)blockIdx.x * 256 + threadIdx.x) * 8;
  float4 a = *(const float4*)(X + i);
  float4 c = *(const float4*)(X + i + 4);
  union { ushort u[8]; short8 v; } r;
  r.u[0] = f2bf(a.x); r.u[1] = f2bf(a.y); r.u[2] = f2bf(a.z); r.u[3] = f2bf(a.w);
  r.u[4] = f2bf(c.x); r.u[5] = f2bf(c.y); r.u[6] = f2bf(c.z); r.u[7] = f2bf(c.w);
  *(short8*)(Xb + i) = r.v;
}

// ---------------- K0b: W fp32 [k][n] -> bf16 W^T [z][n][k] ---------------
__global__ __launch_bounds__(256) void conv_wt_kernel(
    const float* __restrict__ Wq, const float* __restrict__ Wk,
    const float* __restrict__ Wv, ushort* __restrict__ Wt) {
  const int z = blockIdx.z;
  const float* W = (z == 0) ? Wq : ((z == 1) ? Wk : Wv);
  ushort* dst = Wt + (size_t)z * D_ * D_;
  const int k0 = blockIdx.x * 64, n0 = blockIdx.y * 64;
  __shared__ ushort T[64][72];
  const int r = threadIdx.x >> 3, c = (threadIdx.x & 7) * 8;
#pragma unroll
  for (int p = 0; p < 2; ++p) {
    int rr = p * 32 + r;  // k-local
    const float* src = W + (size_t)(k0 + rr) * D_ + n0 + c;
    float4 a = *(const float4*)src;
    float4 b = *(const float4*)(src + 4);
    T[c + 0][rr] = f2bf(a.x); T[c + 1][rr] = f2bf(a.y);
    T[c + 2][rr] = f2bf(a.z); T[c + 3][rr] = f2bf(a.w);
    T[c + 4][rr] = f2bf(b.x); T[c + 5][rr] = f2bf(b.y);
    T[c + 6][rr] = f2bf(b.z); T[c + 7][rr] = f2bf(b.w);
  }
  __syncthreads();
#pragma unroll
  for (int p = 0; p < 2; ++p) {
    int rr = p * 32 + r;  // n-local
    *(short8*)(dst + (size_t)(n0 + rr) * D_ + k0 + c) = *(const short8*)&T[rr][c];
  }
}

// ---------------- K1: fused QKV projection (3 GEMMs, one X pass) ---------
__global__ __launch_bounds__(256) void qkv_kernel(
    const ushort* __restrict__ Xb, const ushort* __restrict__ Wt,
    const float* __restrict__ bq, const float* __restrict__ bk,
    const float* __restrict__ bv, ushort* __restrict__ ws) {
  const int m0 = blockIdx.x * 64;
  const int n0 = blockIdx.y * 64;
  const int tid = threadIdx.x;
  const int lane = tid & 63;
  const int wid = tid >> 6;
  const int lr = lane & 15;
  const int lg = lane >> 4;
  const int m_base = (wid >> 1) * 32;
  const int n_base = (wid & 1) * 32;

  __shared__ union {
    struct { ushort At[64][32]; ushort Bt[3][64][32]; } s;
    ushort bounce[64][72];
  } u;

  f32x4 acc[3][2][2] = {};
  const int l4r = lane >> 2, l4c = (lane & 3) * 8;

  for (int ks = 0; ks < 16; ++ks) {
    const int k0 = ks * 32;
    gld16(Xb + (size_t)(m0 + wid * 16 + l4r) * D_ + k0 + l4c, &u.s.At[wid * 16][0]);
#pragma unroll
    for (int z = 0; z < 3; ++z)
      gld16(Wt + (size_t)z * D_ * D_ + (size_t)(n0 + wid * 16 + l4r) * D_ + k0 + l4c,
            &u.s.Bt[z][wid * 16][0]);
    __syncthreads();
    short8 a[2];
#pragma unroll
    for (int mf = 0; mf < 2; ++mf)
      a[mf] = *(const short8*)&u.s.At[m_base + mf * 16 + lr][lg * 8];
#pragma unroll
    for (int z = 0; z < 3; ++z) {
#pragma unroll
      for (int nf = 0; nf < 2; ++nf) {
        short8 b = *(const short8*)&u.s.Bt[z][n_base + nf * 16 + lr][lg * 8];
#pragma unroll
        for (int mf = 0; mf < 2; ++mf)
          acc[z][mf][nf] = MFMA16(a[mf], b, acc[z][mf][nf]);
      }
    }
    __syncthreads();
  }

  const int b_idx = m0 >> 11;
  const int s0 = m0 & 2047;
#pragma unroll
  for (int z = 0; z < 2; ++z) {
    const float* bias = (z == 0) ? bq : bk;
    ushort* outp = ws + (size_t)z * M_ * D_;
#pragma unroll
    for (int mf = 0; mf < 2; ++mf) {
#pragma unroll
      for (int nf = 0; nf < 2; ++nf) {
        int n = n0 + n_base + nf * 16 + lr;
        float bvv = bias[n];
        int mrow = m_base + mf * 16 + lg * 4;
#pragma unroll
        for (int r = 0; r < 4; ++r)
          outp[(size_t)(m0 + mrow + r) * D_ + n] = f2bf(acc[z][mf][nf][r] + bvv);
      }
    }
  }
  // V: transpose via LDS bounce, coalesced store to [b][d][s]
#pragma unroll
  for (int mf = 0; mf < 2; ++mf) {
#pragma unroll
    for (int nf = 0; nf < 2; ++nf) {
      int nloc = n_base + nf * 16 + lr;
      float bvv = bv[n0 + nloc];
      int mrow = m_base + mf * 16 + lg * 4;
      ushort4 st;
      st.x = f2bf(acc[2][mf][nf][0] + bvv);
      st.y = f2bf(acc[2][mf][nf][1] + bvv);
      st.z = f2bf(acc[2][mf][nf][2] + bvv);
      st.w = f2bf(acc[2][mf][nf][3] + bvv);
      *(ushort4*)&u.bounce[nloc][mrow] = st;
    }
  }
  __syncthreads();
  ushort* vout = ws + 2 * (size_t)M_ * D_;
  const int rr = tid >> 3, cc = (tid & 7) * 8;
#pragma unroll
  for (int p = 0; p < 2; ++p) {
    int d = p * 32 + rr;
    *(short8*)(vout + ((size_t)b_idx * 512 + n0 + d) * 2048 + s0 + cc) =
        *(const short8*)&u.bounce[d][cc];
  }
}

// ---------------- K2: flash attention, QT=64, depth-1 async pipeline -----
__global__ __launch_bounds__(512, 2) void attn_kernel(
    const ushort* __restrict__ Qg, const ushort* __restrict__ Kg,
    const ushort* __restrict__ Vtg, float* __restrict__ Out) {
  const int b = blockIdx.y;              // batch: consecutive bids share batch
  const int q0 = blockIdx.x * QT;
  const int tid = threadIdx.x;
  const int lane = tid & 63;
  const int wid = tid >> 6;
  const int lr = lane & 15;
  const int lg = lane >> 4;
  const int mw = wid >> 1;   // 0..3  S-tile m-frag
  const int nw = wid & 1;    // 0..1  S-tile n-frag

  __shared__ __align__(16) ushort Ks[2][KT * 512];   // 32 rows x 1KB, XOR-swz
  __shared__ __align__(16) ushort Vs[2][512 * KT];   // 512 d-rows x 64B, slot-swz
  __shared__ __align__(16) float Ss[QT][36];
  __shared__ __align__(16) ushort Ps[QT][40];
  __shared__ float mstate[QT], lstate[QT], resc[QT];

  const ushort* Qrow = Qg + ((size_t)b * SREF + q0) * 512;
  const ushort* Krow = Kg + (size_t)b * SREF * 512;
  const ushort* Vrow = Vtg + (size_t)b * 512 * 2048;

  // Q A-fragments in registers (wave's 16 q-rows, full K=512): 64 VGPRs
  short8 qf[16];
  {
    const ushort* qp = Qrow + (size_t)(mw * 16 + lr) * 512 + lg * 8;
#pragma unroll
    for (int ks = 0; ks < 16; ++ks) qf[ks] = *(const short8*)(qp + ks * 32);
  }
  if (tid < QT) { mstate[tid] = -1e30f; lstate[tid] = 0.0f; }

  f32x4 oacc[4][4] = {};

  auto issue = [&](int t, int bi) {
    const int kv0 = t * KT;
#pragma unroll
    for (int ii = 0; ii < 4; ++ii) {  // K: 4 rows/wave (issue K before V!)
      int r = wid * 4 + ii;
      gld16(Krow + (size_t)(kv0 + r) * 512 + ((lane ^ (r & 7)) * 8), &Ks[bi][r * 512]);
    }
#pragma unroll
    for (int ii = 0; ii < 4; ++ii) {  // V: 16 d-rows per issue
      int i = wid * 4 + ii;           // 0..31
      int d = i * 16 + (lane >> 2);
      int cb = (lane & 3) * 16;       // byte col within 64B row
      int s = ((d + (d >> 2)) & 3) << 4;
      gld16(Vrow + (size_t)d * 2048 + t * KT + ((cb ^ s) >> 1), &Vs[bi][i * 512]);
    }
  };

  __syncthreads();   // drain Q loads + state init visible
  issue(0, 0);

  for (int t = 0; t < NT; ++t) {
    const int cur = t & 1;
    const bool more = (t + 1 < NT);
    if (more) issue(t + 1, cur ^ 1);
    if (more) { VM12; } else { VM4; }   // this wave's K(t) landed
    BARRIER();                          // all waves' K(t) landed

    // QK^T: each wave one 16x16 frag of the 64x32 S-tile
    {
      f32x4 sacc = {0.f, 0.f, 0.f, 0.f};
      const int krow = nw * 16 + lr;
      const char* kbase = (const char*)&Ks[cur][krow * 512];
      const int kx = (krow & 7) << 4;
#pragma unroll
      for (int ks = 0; ks < 16; ++ks) {
        short8 bb = *(const short8*)(kbase + ((ks * 64 + lg * 16) ^ kx));
        sacc = MFMA16(qf[ks], bb, sacc);
      }
#pragma unroll
      for (int r = 0; r < 4; ++r)
        Ss[mw * 16 + lg * 4 + r][nw * 16 + lr] = sacc[r];
    }
    BARRIER();

    // softmax: 8 threads/row, 4 cols each
    {
      int row = tid >> 3, ic = tid & 7;
      float4 sv = *(const float4*)&Ss[row][ic * 4];
      const float scale = 0.04419417382415922f;  // 1/sqrt(512)
      float s0 = sv.x * scale, s1 = sv.y * scale, s2 = sv.z * scale, s3 = sv.w * scale;
      float mx = fmaxf(fmaxf(s0, s1), fmaxf(s2, s3));
#pragma unroll
      for (int off = 1; off < 8; off <<= 1) mx = fmaxf(mx, __shfl_xor(mx, off));
      float mold = mstate[row];
      float mnew = fmaxf(mold, mx);
      float p0 = __expf(s0 - mnew), p1 = __expf(s1 - mnew);
      float p2 = __expf(s2 - mnew), p3 = __expf(s3 - mnew);
      float psum = p0 + p1 + p2 + p3;
#pragma unroll
      for (int off = 1; off < 8; off <<= 1) psum += __shfl_xor(psum, off);
      ushort4 pb;
      pb.x = f2bf(p0); pb.y = f2bf(p1); pb.z = f2bf(p2); pb.w = f2bf(p3);
      *(ushort4*)&Ps[row][ic * 4] = pb;
      if (ic == 0) {
        float sc = __expf(mold - mnew);
        resc[row] = sc;
        mstate[row] = mnew;
        lstate[row] = lstate[row] * sc + psum;
      }
    }
    if (more) { VM8; } else { VM0; }    // this wave's V(t) landed
    BARRIER();                          // all waves' V(t) + P visible

    // PV: rescale O, accumulate; wave owns d-chunk [wid*64, +64)
#pragma unroll
    for (int mf = 0; mf < 4; ++mf) {
      f32x4 rv;
#pragma unroll
      for (int r = 0; r < 4; ++r) rv[r] = resc[mf * 16 + lg * 4 + r];
#pragma unroll
      for (int nf = 0; nf < 4; ++nf) oacc[mf][nf] *= rv;
    }
    {
      short8 pA[4];
#pragma unroll
      for (int mf = 0; mf < 4; ++mf)
        pA[mf] = *(const short8*)&Ps[mf * 16 + lr][lg * 8];
#pragma unroll
      for (int nf = 0; nf < 4; ++nf) {
        int d = wid * 64 + nf * 16 + lr;
        int s = ((d + (d >> 2)) & 3) << 4;
        short8 vB = *(const short8*)((const char*)&Vs[cur][0] + d * 64 + ((lg * 16) ^ s));
#pragma unroll
        for (int mf = 0; mf < 4; ++mf) oacc[mf][nf] = MFMA16(pA[mf], vB, oacc[mf][nf]);
      }
    }
    BARRIER();  // all waves done reading buf[cur] before t+1 issues into it
  }

  // epilogue: O / l
#pragma unroll
  for (int mf = 0; mf < 4; ++mf) {
#pragma unroll
    for (int r = 0; r < 4; ++r) {
      int row = mf * 16 + lg * 4 + r;
      float inv = 1.0f / lstate[row];
      float* op = Out + ((size_t)b * SREF + q0 + row) * 512 + wid * 64;
#pragma unroll
      for (int nf = 0; nf < 4; ++nf) op[nf * 16 + lr] = oacc[mf][nf][r] * inv;
    }
  }
}

extern "C" void kernel_launch(void* const* d_in, const int* in_sizes, int n_in,
                              void* d_out, int out_size, void* d_ws, size_t ws_size,
                              hipStream_t stream) {
  const float* X  = (const float*)d_in[0];
  const float* Wq = (const float*)d_in[1];
  const float* bq = (const float*)d_in[2];
  const float* Wk = (const float*)d_in[3];
  const float* bk = (const float*)d_in[4];
  const float* Wv = (const float*)d_in[5];
  const float* bv = (const float*)d_in[6];
  ushort* ws = (ushort*)d_ws;
  float* out = (float*)d_out;

  // d_out doubles as scratch for bf16 X and W^T until attn overwrites it.
  ushort* Xb = (ushort*)d_out;
  ushort* Wt = Xb + (size_t)M_ * D_;

  conv_x_kernel<<<dim3(M_ * D_ / (256 * 8)), dim3(256), 0, stream>>>(X, Xb);
  conv_wt_kernel<<<dim3(8, 8, 3), dim3(256), 0, stream>>>(Wq, Wk, Wv, Wt);

  dim3 g1(M_ / 64, D_ / 64), b1(256);
  qkv_kernel<<<g1, b1, 0, stream>>>(Xb, Wt, bq, bk, bv, ws);

  attn_kernel<<<dim3(SREF / QT, 8), dim3(512), 0, stream>>>(
      ws, ws + (size_t)M_ * D_, ws + 2 * (size_t)M_ * D_, out);
}

// Round 4
// 186.684 us; speedup vs baseline: 2.0008x; 1.1515x over previous
//
#include <hip/hip_runtime.h>
#include <hip/hip_bf16.h>
#include <stdint.h>

typedef __attribute__((ext_vector_type(8))) short short8;
typedef __attribute__((ext_vector_type(4))) float f32x4;

#define MFMA16(a, b, c) __builtin_amdgcn_mfma_f32_16x16x32_bf16(a, b, c, 0, 0, 0)

#define D_ 512
#define M_ 16384
#define SREF 2048
#define QT 64
#define KT 32
#define NT (SREF / KT)

#define VM0  asm volatile("s_waitcnt vmcnt(0)" ::: "memory")
#define LGKM0 asm volatile("s_waitcnt lgkmcnt(0)" ::: "memory")
#define BARRIER() do { asm volatile("s_waitcnt lgkmcnt(0)" ::: "memory"); \
                       __builtin_amdgcn_s_barrier(); \
                       asm volatile("" ::: "memory"); } while (0)

__device__ __forceinline__ ushort f2bf(float f) {
  union { float f; uint32_t u; } v; v.f = f;
  uint32_t r = v.u + 0x7fffu + ((v.u >> 16) & 1u);
  return (ushort)(r >> 16);
}

__device__ __forceinline__ void gld16(const void* g, void* l) {
  __builtin_amdgcn_global_load_lds(
      (const __attribute__((address_space(1))) void*)g,
      (__attribute__((address_space(3))) void*)l, 16, 0, 0);
}

// ---------------- K0a: X fp32 -> bf16 ------------------------------------
__global__ __launch_bounds__(256) void conv_x_kernel(
    const float* __restrict__ X, ushort* __restrict__ Xb) {
  size_t i = ((size_t)blockIdx.x * 256 + threadIdx.x) * 8;
  float4 a = *(const float4*)(X + i);
  float4 c = *(const float4*)(X + i + 4);
  union { ushort u[8]; short8 v; } r;
  r.u[0] = f2bf(a.x); r.u[1] = f2bf(a.y); r.u[2] = f2bf(a.z); r.u[3] = f2bf(a.w);
  r.u[4] = f2bf(c.x); r.u[5] = f2bf(c.y); r.u[6] = f2bf(c.z); r.u[7] = f2bf(c.w);
  *(short8*)(Xb + i) = r.v;
}

// ---------------- K0b: W fp32 [k][n] -> bf16 W^T [z][n][k] ---------------
__global__ __launch_bounds__(256) void conv_wt_kernel(
    const float* __restrict__ Wq, const float* __restrict__ Wk,
    const float* __restrict__ Wv, ushort* __restrict__ Wt) {
  const int z = blockIdx.z;
  const float* W = (z == 0) ? Wq : ((z == 1) ? Wk : Wv);
  ushort* dst = Wt + (size_t)z * D_ * D_;
  const int k0 = blockIdx.x * 64, n0 = blockIdx.y * 64;
  __shared__ ushort T[64][72];
  const int r = threadIdx.x >> 3, c = (threadIdx.x & 7) * 8;
#pragma unroll
  for (int p = 0; p < 2; ++p) {
    int rr = p * 32 + r;
    const float* src = W + (size_t)(k0 + rr) * D_ + n0 + c;
    float4 a = *(const float4*)src;
    float4 b = *(const float4*)(src + 4);
    T[c + 0][rr] = f2bf(a.x); T[c + 1][rr] = f2bf(a.y);
    T[c + 2][rr] = f2bf(a.z); T[c + 3][rr] = f2bf(a.w);
    T[c + 4][rr] = f2bf(b.x); T[c + 5][rr] = f2bf(b.y);
    T[c + 6][rr] = f2bf(b.z); T[c + 7][rr] = f2bf(b.w);
  }
  __syncthreads();
#pragma unroll
  for (int p = 0; p < 2; ++p) {
    int rr = p * 32 + r;
    *(short8*)(dst + (size_t)(n0 + rr) * D_ + k0 + c) = *(const short8*)&T[rr][c];
  }
}

// ---------------- K1: fused QKV projection (3 GEMMs, one X pass) ---------
// z=0: Q (pre-scaled by 1/sqrt(512)), z=1: K row-major; z=2: V^T [b][d][s]
__global__ __launch_bounds__(256) void qkv_kernel(
    const ushort* __restrict__ Xb, const ushort* __restrict__ Wt,
    const float* __restrict__ bq, const float* __restrict__ bk,
    const float* __restrict__ bv, ushort* __restrict__ ws) {
  const int m0 = blockIdx.x * 64;
  const int n0 = blockIdx.y * 64;
  const int tid = threadIdx.x;
  const int lane = tid & 63;
  const int wid = tid >> 6;
  const int lr = lane & 15;
  const int lg = lane >> 4;
  const int m_base = (wid >> 1) * 32;
  const int n_base = (wid & 1) * 32;

  __shared__ union {
    struct { ushort At[64][32]; ushort Bt[3][64][32]; } s;
    ushort bounce[64][72];
  } u;

  f32x4 acc[3][2][2] = {};
  const int l4r = lane >> 2, l4c = (lane & 3) * 8;

  for (int ks = 0; ks < 16; ++ks) {
    const int k0 = ks * 32;
    gld16(Xb + (size_t)(m0 + wid * 16 + l4r) * D_ + k0 + l4c, &u.s.At[wid * 16][0]);
#pragma unroll
    for (int z = 0; z < 3; ++z)
      gld16(Wt + (size_t)z * D_ * D_ + (size_t)(n0 + wid * 16 + l4r) * D_ + k0 + l4c,
            &u.s.Bt[z][wid * 16][0]);
    __syncthreads();
    short8 a[2];
#pragma unroll
    for (int mf = 0; mf < 2; ++mf)
      a[mf] = *(const short8*)&u.s.At[m_base + mf * 16 + lr][lg * 8];
#pragma unroll
    for (int z = 0; z < 3; ++z) {
#pragma unroll
      for (int nf = 0; nf < 2; ++nf) {
        short8 b = *(const short8*)&u.s.Bt[z][n_base + nf * 16 + lr][lg * 8];
#pragma unroll
        for (int mf = 0; mf < 2; ++mf)
          acc[z][mf][nf] = MFMA16(a[mf], b, acc[z][mf][nf]);
      }
    }
    __syncthreads();
  }

  const int b_idx = m0 >> 11;
  const int s0 = m0 & 2047;
  const float qscale = 0.04419417382415922f;  // 1/sqrt(512)
#pragma unroll
  for (int z = 0; z < 2; ++z) {
    const float* bias = (z == 0) ? bq : bk;
    ushort* outp = ws + (size_t)z * M_ * D_;
#pragma unroll
    for (int mf = 0; mf < 2; ++mf) {
#pragma unroll
      for (int nf = 0; nf < 2; ++nf) {
        int n = n0 + n_base + nf * 16 + lr;
        float bvv = bias[n];
        int mrow = m_base + mf * 16 + lg * 4;
#pragma unroll
        for (int r = 0; r < 4; ++r) {
          float v = acc[z][mf][nf][r] + bvv;
          if (z == 0) v *= qscale;
          outp[(size_t)(m0 + mrow + r) * D_ + n] = f2bf(v);
        }
      }
    }
  }
#pragma unroll
  for (int mf = 0; mf < 2; ++mf) {
#pragma unroll
    for (int nf = 0; nf < 2; ++nf) {
      int nloc = n_base + nf * 16 + lr;
      float bvv = bv[n0 + nloc];
      int mrow = m_base + mf * 16 + lg * 4;
      ushort4 st;
      st.x = f2bf(acc[2][mf][nf][0] + bvv);
      st.y = f2bf(acc[2][mf][nf][1] + bvv);
      st.z = f2bf(acc[2][mf][nf][2] + bvv);
      st.w = f2bf(acc[2][mf][nf][3] + bvv);
      *(ushort4*)&u.bounce[nloc][mrow] = st;
    }
  }
  __syncthreads();
  ushort* vout = ws + 2 * (size_t)M_ * D_;
  const int rr = tid >> 3, cc = (tid & 7) * 8;
#pragma unroll
  for (int p = 0; p < 2; ++p) {
    int d = p * 32 + rr;
    *(short8*)(vout + ((size_t)b_idx * 512 + n0 + d) * 2048 + s0 + cc) =
        *(const short8*)&u.bounce[d][cc];
  }
}

// ---------------- K2: flash attention, 2 barriers/tile -------------------
__global__ __launch_bounds__(512, 2) void attn_kernel(
    const ushort* __restrict__ Qg, const ushort* __restrict__ Kg,
    const ushort* __restrict__ Vtg, float* __restrict__ Out) {
  const int b = blockIdx.y;
  const int q0 = blockIdx.x * QT;
  const int tid = threadIdx.x;
  const int lane = tid & 63;
  const int wid = tid >> 6;
  const int lr = lane & 15;
  const int lg = lane >> 4;
  const int mw = wid >> 1;   // 0..3  S-tile m-frag
  const int nw = wid & 1;    // 0..1  S-tile n-frag

  __shared__ __align__(16) ushort Ks[2][KT * 512];   // K rows, 1KB, XOR-swz
  __shared__ __align__(16) ushort Vs[2][512 * KT];   // V^T d-rows, 64B, slot-swz
  __shared__ __align__(16) char  SsB[64 * 144];      // S, 16B-block XOR (row&7)
  __shared__ __align__(16) ushort PsB[64 * 32];      // P, 16B-block XOR (row&3)
  __shared__ float mstate[QT], lstate[QT], resc[QT];

  const ushort* Qrow = Qg + ((size_t)b * SREF + q0) * 512;
  const ushort* Krow = Kg + (size_t)b * SREF * 512;
  const ushort* Vrow = Vtg + (size_t)b * 512 * 2048;

  // Q A-fragments in registers (wave's 16 q-rows, full K=512): 64 VGPRs
  short8 qf[16];
  {
    const ushort* qp = Qrow + (size_t)(mw * 16 + lr) * 512 + lg * 8;
#pragma unroll
    for (int ks = 0; ks < 16; ++ks) qf[ks] = *(const short8*)(qp + ks * 32);
  }
  if (tid < QT) { mstate[tid] = -1e30f; lstate[tid] = 0.0f; }

  f32x4 oacc[4][4] = {};

  auto issueK = [&](int t, int bi) {
#pragma unroll
    for (int ii = 0; ii < 4; ++ii) {
      int r = wid * 4 + ii;
      gld16(Krow + (size_t)(t * KT + r) * 512 + ((lane ^ (r & 7)) * 8), &Ks[bi][r * 512]);
    }
  };
  auto issueV = [&](int t, int bi) {
#pragma unroll
    for (int ii = 0; ii < 4; ++ii) {
      int i = wid * 4 + ii;               // wave stages exactly its own d-rows
      int d = i * 16 + (lane >> 2);
      int cb = (lane & 3) * 16;
      int s = ((d + (d >> 2)) & 3) << 4;
      gld16(Vrow + (size_t)d * 2048 + t * KT + ((cb ^ s) >> 1), &Vs[bi][i * 512]);
    }
  };
  auto doPV = [&](int vbi) {
    // rescale O by resc, then O += P V   (wave owns d-chunk [wid*64,+64))
#pragma unroll
    for (int mf = 0; mf < 4; ++mf) {
      f32x4 rv;
#pragma unroll
      for (int r = 0; r < 4; ++r) rv[r] = resc[mf * 16 + lg * 4 + r];
#pragma unroll
      for (int nf = 0; nf < 4; ++nf) oacc[mf][nf] *= rv;
    }
    short8 pA[4];
#pragma unroll
    for (int mf = 0; mf < 4; ++mf) {
      int row = mf * 16 + lr;
      pA[mf] = *(const short8*)((const char*)PsB + row * 64 + ((lg ^ (row & 3)) << 4));
    }
    __builtin_amdgcn_s_setprio(1);
#pragma unroll
    for (int nf = 0; nf < 4; ++nf) {
      int d = wid * 64 + nf * 16 + lr;
      int s = ((d + (d >> 2)) & 3) << 4;
      short8 vB = *(const short8*)((const char*)&Vs[vbi][0] + d * 64 + ((lg * 16) ^ s));
#pragma unroll
      for (int mf = 0; mf < 4; ++mf) oacc[mf][nf] = MFMA16(pA[mf], vB, oacc[mf][nf]);
    }
    __builtin_amdgcn_s_setprio(0);
  };

  issueK(0, 0);
  issueV(0, 0);
  VM0;
  BARRIER();

  for (int t = 0; t < NT; ++t) {
    const int cur = t & 1;
    // ---- window A: PV(t-1) || K/V(t+1) issue || QK^T(t) ----
    if (t + 1 < NT) issueK(t + 1, cur ^ 1);
    if (t > 0) {
      doPV(cur ^ 1);          // V(t-1) lives in Vs[(t-1)&1] = cur^1
      LGKM0;                  // own V-buffer reads done before re-staging it
    }
    if (t + 1 < NT) issueV(t + 1, cur ^ 1);
    {
      f32x4 s0v = {0.f, 0.f, 0.f, 0.f}, s1v = {0.f, 0.f, 0.f, 0.f};
      const int krow = nw * 16 + lr;
      const char* kbase = (const char*)&Ks[cur][krow * 512];
      const int kx = (krow & 7) << 4;
      __builtin_amdgcn_s_setprio(1);
#pragma unroll
      for (int ks = 0; ks < 16; ks += 2) {
        short8 b0 = *(const short8*)(kbase + ((ks * 64 + lg * 16) ^ kx));
        short8 b1 = *(const short8*)(kbase + (((ks + 1) * 64 + lg * 16) ^ kx));
        s0v = MFMA16(qf[ks], b0, s0v);
        s1v = MFMA16(qf[ks + 1], b1, s1v);
      }
      __builtin_amdgcn_s_setprio(0);
      s0v += s1v;
#pragma unroll
      for (int r = 0; r < 4; ++r) {
        int row = mw * 16 + lg * 4 + r;
        int c = nw * 16 + lr;
        int byte = row * 144 + ((((c >> 2) ^ (row & 7)) << 4) | ((c & 3) << 2));
        *(float*)(SsB + byte) = s0v[r];
      }
    }
    BARRIER();  // B2: S visible; all QK^T(t) reads of Ks done

    // ---- window B: softmax ----
    {
      int row = tid >> 3, ic = tid & 7;
      float4 sv = *(const float4*)(SsB + row * 144 + ((ic ^ (row & 7)) << 4));
      float s0 = sv.x, s1 = sv.y, s2 = sv.z, s3 = sv.w;
      float mx = fmaxf(fmaxf(s0, s1), fmaxf(s2, s3));
#pragma unroll
      for (int off = 1; off < 8; off <<= 1) mx = fmaxf(mx, __shfl_xor(mx, off));
      float mold = mstate[row];
      float mnew = fmaxf(mold, mx);
      float p0 = __expf(s0 - mnew), p1 = __expf(s1 - mnew);
      float p2 = __expf(s2 - mnew), p3 = __expf(s3 - mnew);
      float psum = p0 + p1 + p2 + p3;
#pragma unroll
      for (int off = 1; off < 8; off <<= 1) psum += __shfl_xor(psum, off);
      ushort4 pb;
      pb.x = f2bf(p0); pb.y = f2bf(p1); pb.z = f2bf(p2); pb.w = f2bf(p3);
      *(ushort4*)((char*)PsB + row * 64 + (((ic >> 1) ^ (row & 3)) << 4) + (ic & 1) * 8) = pb;
      if (ic == 0) {
        float sc = __expf(mold - mnew);
        resc[row] = sc;
        mstate[row] = mnew;
        lstate[row] = lstate[row] * sc + psum;
      }
    }
    VM0;        // K(t+1) + V(t+1) landed (issued a window ago)
    BARRIER();  // B3: P/resc visible + all staged tiles certified landed
  }

  doPV((NT - 1) & 1);  // final PV

  // epilogue: O / l
#pragma unroll
  for (int mf = 0; mf < 4; ++mf) {
#pragma unroll
    for (int r = 0; r < 4; ++r) {
      int row = mf * 16 + lg * 4 + r;
      float inv = 1.0f / lstate[row];
      float* op = Out + ((size_t)b * SREF + q0 + row) * 512 + wid * 64;
#pragma unroll
      for (int nf = 0; nf < 4; ++nf) op[nf * 16 + lr] = oacc[mf][nf][r] * inv;
    }
  }
}

extern "C" void kernel_launch(void* const* d_in, const int* in_sizes, int n_in,
                              void* d_out, int out_size, void* d_ws, size_t ws_size,
                              hipStream_t stream) {
  const float* X  = (const float*)d_in[0];
  const float* Wq = (const float*)d_in[1];
  const float* bq = (const float*)d_in[2];
  const float* Wk = (const float*)d_in[3];
  const float* bk = (const float*)d_in[4];
  const float* Wv = (const float*)d_in[5];
  const float* bv = (const float*)d_in[6];
  ushort* ws = (ushort*)d_ws;
  float* out = (float*)d_out;

  ushort* Xb = (ushort*)d_out;
  ushort* Wt = Xb + (size_t)M_ * D_;

  conv_x_kernel<<<dim3(M_ * D_ / (256 * 8)), dim3(256), 0, stream>>>(X, Xb);
  conv_wt_kernel<<<dim3(8, 8, 3), dim3(256), 0, stream>>>(Wq, Wk, Wv, Wt);

  dim3 g1(M_ / 64, D_ / 64), b1(256);
  qkv_kernel<<<g1, b1, 0, stream>>>(Xb, Wt, bq, bk, bv, ws);

  attn_kernel<<<dim3(SREF / QT, 8), dim3(512), 0, stream>>>(
      ws, ws + (size_t)M_ * D_, ws + 2 * (size_t)M_ * D_, out);
}